// Round 5
// baseline (179.045 us; speedup 1.0000x reference)
//
#include <hip/hip_runtime.h>
#include <math.h>

// Problem constants
#define NS 64    // sentences
#define NW 64    // words per sentence
#define NE 300   // embedding dim
#define NH 50    // hidden
#define NO 5     // output classes
#define NPROD 64 // producer blocks (one per sentence)
#define TPB 192  // 3 waves per block

// d_ws layout (floats):
//   [0]          flag1 (int): producers-done counter
//   [1]          flag2 (int): scan-blocks-done counter
//   [64 ..]      Xg: 2*64*3*50 = 19200 floats (gate x-preactivations)
//   [64+19200..] gsum: 100 floats (per-direction mean hidden)

__device__ __forceinline__ float fast_tanh(float x) {
  x = fminf(15.f, fmaxf(-15.f, x));
  float e = __expf(2.f * x);
  return (e - 1.f) / (e + 1.f);
}
__device__ __forceinline__ float fast_sigmoid(float x) {
  return 1.f / (1.f + __expf(-x));
}

__global__ __launch_bounds__(TPB, 1) void k_all(
    const int* __restrict__ doc, const float* __restrict__ emb,
    const float* __restrict__ Wword, const float* __restrict__ bword,
    const float* __restrict__ w1, const float* __restrict__ b1,
    const float* __restrict__ w2, const float* __restrict__ b2,
    const float* __restrict__ w3, const float* __restrict__ b3,
    const float* __restrict__ Wfi, const float* __restrict__ bfi,
    const float* __restrict__ Wff, const float* __restrict__ bff,
    const float* __restrict__ Wfg, const float* __restrict__ bfg,
    const float* __restrict__ Wbi, const float* __restrict__ bbi,
    const float* __restrict__ Wbf, const float* __restrict__ bbf,
    const float* __restrict__ Wbg, const float* __restrict__ bbg,
    const float* __restrict__ Wout, const float* __restrict__ bout,
    float* __restrict__ ws, float* __restrict__ out)
{
  int*   flag1 = (int*)ws;
  int*   flag2 = (int*)ws + 1;
  float* XgG   = ws + 64;
  float* gsumG = ws + 64 + 2 * NS * 3 * NH;

  // Scan-side LDS
  __shared__ float Xlds[NS * 3 * NH];   // 38400 B, one direction's X
  __shared__ float h_sh[3][64];         // WAVE-PRIVATE h copies (row = wave)
  __shared__ float gate_sh[2][3][64];   // parity double-buffered gates
  __shared__ int   last_sh;
  // Producer-side LDS
  __shared__ int   idxs[NW];
  __shared__ float sv[5][304];          // 0: word-sum; 1..4: rows 0,1,62,63
  __shared__ float dots[5][NH];
  __shared__ float reps_s[NH];

  const int tid = threadIdx.x;
  const int b   = blockIdx.x;

  if (b < NPROD) {
    // =============================== producer ===============================
    const int s = b;
    if (tid < NW) idxs[tid] = doc[s * NW + tid];
    __syncthreads();

    // Phase B: column sums of the 64 gathered embedding rows (coalesced in e).
    for (int e = tid; e < NE; e += TPB) {
      float acc = 0.f;
#pragma unroll 16
      for (int w = 0; w < NW; ++w)
        acc += emb[(size_t)idxs[w] * NE + e];
      sv[0][e] = acc;
      sv[1][e] = emb[(size_t)idxs[0]  * NE + e];
      sv[2][e] = emb[(size_t)idxs[1]  * NE + e];
      sv[3][e] = emb[(size_t)idxs[62] * NE + e];
      sv[4][e] = emb[(size_t)idxs[63] * NE + e];
    }
    __syncthreads();

    // Phase C: 5 families x 50 outputs, 300-dots against W_word rows.
    for (int task = tid; task < 5 * NH; task += TPB) {
      const int fam = task / NH, i = task % NH;
      const float4* v4 = (const float4*)&sv[fam][0];
      const float4* w4 = (const float4*)(Wword + (size_t)i * NE);
      float a0 = 0.f, a1 = 0.f;
#pragma unroll
      for (int c = 0; c < NE / 4; ++c) {
        const float4 v = v4[c], w = w4[c];
        a0 += v.x * w.x + v.y * w.y;
        a1 += v.z * w.z + v.w * w.w;
      }
      dots[fam][i] = a0 + a1;
    }
    __syncthreads();

    // Phase D: conv means + tanh + average -> reps_s
    if (tid < NH) {
      const int o = tid;
      float m1 = 0.f, m2 = 0.f, m3 = 0.f;
      for (int i = 0; i < NH; ++i) {
        const float bw    = bword[i];
        const float total = dots[0][i] + 64.f * bw;
        const float e0  = dots[1][i] + bw;
        const float e1  = dots[2][i] + bw;
        const float e62 = dots[3][i] + bw;
        const float e63 = dots[4][i] + bw;
        m1 += w1[o * NH + i] * total;
        m2 += w2[(o * NH + i) * 2 + 0] * (total - e63)
            + w2[(o * NH + i) * 2 + 1] * (total - e0);
        m3 += w3[(o * NH + i) * 3 + 0] * (total - e62 - e63)
            + w3[(o * NH + i) * 3 + 1] * (total - e0 - e63)
            + w3[(o * NH + i) * 3 + 2] * (total - e0 - e1);
      }
      m1 = b1[o] + m1 * (1.f / 64.f);
      m2 = b2[o] + m2 * (1.f / 63.f);
      m3 = b3[o] + m3 * (1.f / 62.f);
      reps_s[o] = (fast_tanh(m1) + fast_tanh(m2) + fast_tanh(m3)) * (1.f / 3.f);
    }
    __syncthreads();

    // Phase E: x-part gate preactivations for both directions.
    for (int task = tid; task < 6 * NH; task += TPB) {
      const int dg = task / NH, j = task % NH;
      const float* Wp; const float* bp;
      switch (dg) {
        case 0: Wp = Wfi; bp = bfi; break;
        case 1: Wp = Wff; bp = bff; break;
        case 2: Wp = Wfg; bp = bfg; break;
        case 3: Wp = Wbi; bp = bbi; break;
        case 4: Wp = Wbf; bp = bbf; break;
        default: Wp = Wbg; bp = bbg; break;
      }
      float acc = bp[j];
      for (int k = 0; k < NH; ++k) acc += Wp[j * 100 + k] * reps_s[k];
      const int dir = dg / 3, gate = dg % 3;
      XgG[((dir * NS + s) * 3 + gate) * NH + j] = acc;
    }
    __syncthreads();   // all waves' Xg writes retired

    if (tid == 0) {
      __threadfence(); // write back so other XCDs see Xg
      __hip_atomic_fetch_add(flag1, 1, __ATOMIC_RELEASE, __HIP_MEMORY_SCOPE_AGENT);
    }
    return;
  }

  // ================================ scan ===================================
  const int d    = b - NPROD;           // direction 0=fwd, 1=bwd
  const int wid  = tid >> 6, lane = tid & 63;
  const int g    = wid;                 // gate: 0=i, 1=f, 2=g
  const int j    = (lane < NH) ? lane : 0;

  const float* Wp = (d == 0) ? ((g == 0) ? Wfi : (g == 1) ? Wff : Wfg)
                             : ((g == 0) ? Wbi : (g == 1) ? Wbf : Wbg);

  // 50 h-weights per lane (+2 zero pad for the float4 dot) — loaded while
  // producers are still running (overlapped with the spin-wait).
  float wk[52];
#pragma unroll
  for (int k = 0; k < NH; ++k) wk[k] = Wp[j * 100 + 50 + k];
  wk[50] = 0.f; wk[51] = 0.f;
  h_sh[wid][lane] = 0.f;   // each wave inits its own private h row

  if (tid == 0) {
    while (__hip_atomic_load(flag1, __ATOMIC_ACQUIRE, __HIP_MEMORY_SCOPE_AGENT) < NPROD)
      __builtin_amdgcn_s_sleep(2);
    __threadfence();   // invalidate stale lines before Xg reads
  }
  __syncthreads();

  // Stage this direction's X into LDS: 9600 floats, coalesced float4.
  {
    const float4* src = (const float4*)(XgG + d * NS * 3 * NH);
    float4* dst = (float4*)Xlds;
    for (int i = tid; i < NS * 3 * NH / 4; i += TPB) dst[i] = src[i];
  }
  __syncthreads();

  // 64 sequential steps, ONE barrier per step:
  //   dot(own h copy) -> act -> write gate[parity] -> barrier ->
  //   read 3 gates -> update hj (redundant per wave) -> write own h copy
  // gate parity buffering removes the write-after-read hazard that needed
  // the second barrier; wave-private h removes the cross-wave h dependency.
  const int t0 = d ? (NS - 1) : 0;
  float xa = Xlds[(t0 * 3 + g) * NH + j];
  float hj = 0.f, hs = 0.f;
  for (int n = 0; n < NS; ++n) {
    float a = xa;

    const float4* h4 = (const float4*)&h_sh[g][0];  // own copy, broadcast reads
    float a0 = 0.f, a1 = 0.f;
#pragma unroll
    for (int c = 0; c < 13; ++c) {
      const float4 hv = h4[c];
      a0 += wk[4 * c + 0] * hv.x;
      a1 += wk[4 * c + 1] * hv.y;
      a0 += wk[4 * c + 2] * hv.z;
      a1 += wk[4 * c + 3] * hv.w;
    }
    a += a0 + a1;

    const float act = (g == 2) ? fast_tanh(a) : fast_sigmoid(a);
    const int p = n & 1;
    if (lane < NH) gate_sh[p][g][lane] = act;

    if (n < NS - 1) {                    // prefetch next X before the barrier
      const int t = d ? (NS - 2 - n) : (n + 1);
      xa = Xlds[(t * 3 + g) * NH + j];
    }
    __syncthreads();                     // single rendezvous per step

    const float iv = gate_sh[p][0][j];
    const float fv = gate_sh[p][1][j];
    const float gv = gate_sh[p][2][j];
    hj = fast_tanh(iv * gv + fv * hj);   // redundant across the 3 waves
    hs += hj;
    if (lane < NH) h_sh[g][lane] = hj;   // own copy; next read is same-wave
  }

  if (g == 0 && lane < NH) gsumG[d * NH + lane] = hs * (1.f / 64.f);
  __syncthreads();   // gsum writes retired

  if (tid == 0) {
    __threadfence();
    const int old = __hip_atomic_fetch_add(flag2, 1, __ATOMIC_ACQ_REL,
                                           __HIP_MEMORY_SCOPE_AGENT);
    if (old == 1) __threadfence();  // acquire other direction's gsum
    last_sh = (old == 1);
  }
  __syncthreads();
  if (!last_sh) return;

  // Epilogue (last scan block, wave 0): logits + softmax
  if (wid == 0) {
    float lg = 0.f;
    if (lane < NO) {
      float acc = bout[lane];
      for (int k = 0; k < 2 * NH; ++k) acc += Wout[lane * 2 * NH + k] * gsumG[k];
      lg = acc;
    }
    const float l0 = __shfl(lg, 0), l1 = __shfl(lg, 1), l2 = __shfl(lg, 2),
                l3 = __shfl(lg, 3), l4 = __shfl(lg, 4);
    if (lane == 0) {
      const float m = fmaxf(fmaxf(fmaxf(l0, l1), fmaxf(l2, l3)), l4);
      const float e0 = __expf(l0 - m), e1 = __expf(l1 - m), e2 = __expf(l2 - m),
                  e3 = __expf(l3 - m), e4 = __expf(l4 - m);
      const float se = e0 + e1 + e2 + e3 + e4;
      out[0] = e0 / se; out[1] = e1 / se; out[2] = e2 / se;
      out[3] = e3 / se; out[4] = e4 / se;
    }
  }
}

// ------------------------- clock diagnostic kernel -------------------------
// Duration encodes SCLK. Phase 1: spin until clock64() (shader-clock domain)
// advances 120k ticks -> 50us @2.4GHz, 218us @550MHz. Phase 2: 24k DEPENDENT
// FMAs (4 cyc dep latency) -> 40us @2.4GHz, 175us @550MHz. Total:
//   ~90us  => clock high (2.4GHz)
//   ~390us => clock low  (~550MHz)
//   ~225us => memtime constant-rate but VALU slow (clock still low)
// Writes nothing; deterministic output (none); graph-safe.
__global__ __launch_bounds__(64) void k_spin() {
  const unsigned long long t0 = clock64();
  while (clock64() - t0 < 120000ULL) {}
  float r = 1.0f;
  for (int i = 0; i < 1500; ++i) {
#pragma unroll
    for (int u = 0; u < 16; ++u)
      r = __builtin_fmaf(r, 1.0000001f, 1e-9f);
    asm volatile("" :: "v"(r));   // keep the chain live (no DCE)
  }
}

extern "C" void kernel_launch(void* const* d_in, const int* in_sizes, int n_in,
                              void* d_out, int out_size, void* d_ws, size_t ws_size,
                              hipStream_t stream) {
  const int*   doc   = (const int*)  d_in[0];
  const float* emb   = (const float*)d_in[1];
  const float* Wword = (const float*)d_in[2];
  const float* bword = (const float*)d_in[3];
  const float* w1    = (const float*)d_in[4];
  const float* b1    = (const float*)d_in[5];
  const float* w2    = (const float*)d_in[6];
  const float* b2    = (const float*)d_in[7];
  const float* w3    = (const float*)d_in[8];
  const float* b3    = (const float*)d_in[9];
  const float* Wfi   = (const float*)d_in[10];
  const float* bfi   = (const float*)d_in[11];
  const float* Wff   = (const float*)d_in[12];
  const float* bff   = (const float*)d_in[13];
  const float* Wfg   = (const float*)d_in[14];
  const float* bfg   = (const float*)d_in[15];
  const float* Wbi   = (const float*)d_in[16];
  const float* bbi   = (const float*)d_in[17];
  const float* Wbf   = (const float*)d_in[18];
  const float* bbf   = (const float*)d_in[19];
  const float* Wbg   = (const float*)d_in[20];
  const float* bbg   = (const float*)d_in[21];
  const float* Wout  = (const float*)d_in[22];
  const float* bout  = (const float*)d_in[23];

  // zero the two sync flags (graph-capturable async memset)
  hipMemsetAsync(d_ws, 0, 8, stream);

  k_all<<<dim3(NPROD + 2), dim3(TPB), 0, stream>>>(
      doc, emb, Wword, bword, w1, b1, w2, b2, w3, b3,
      Wfi, bfi, Wff, bff, Wfg, bfg, Wbi, bbi, Wbf, bbf, Wbg, bbg,
      Wout, bout, (float*)d_ws, (float*)d_out);

  k_spin<<<dim3(1), dim3(64), 0, stream>>>();
}

// Round 6
// 78.296 us; speedup vs baseline: 2.2868x; 2.2868x over previous
//
#include <hip/hip_runtime.h>
#include <math.h>

// Problem constants
#define NS 64    // sentences
#define NW 64    // words per sentence
#define NE 300   // embedding dim
#define NH 50    // hidden
#define NO 5     // output classes
#define NPROD 64 // producer blocks (one per sentence)
#define TPB 192  // 3 waves per block

// Session facts (measured):
//  - R5 k_spin: SCLK ~2.0 GHz even when near-idle -> low-clock theory refuted.
//  - R3->R5: removing one LDS rendezvous/step saved ~14 us -> serialized LDS
//    round-trips dominate the scan. This round removes ALL in-loop LDS.

// d_ws layout (floats):
//   [0]     flag1 (int): producers-done counter
//   [64..]  Xg: 2*64*3*50 = 19200 floats (gate x-preactivations)

__device__ __forceinline__ float fast_tanh(float x) {
  x = fminf(15.f, fmaxf(-15.f, x));
  float e = __expf(2.f * x);
  return (e - 1.f) / (e + 1.f);
}
__device__ __forceinline__ float fast_sigmoid(float x) {
  return 1.f / (1.f + __expf(-x));
}
__device__ __forceinline__ float lane_bcast(float v, int k) {
  return __uint_as_float(__builtin_amdgcn_readlane(__float_as_uint(v), k));
}

__global__ __launch_bounds__(TPB, 1) void k_all(
    const int* __restrict__ doc, const float* __restrict__ emb,
    const float* __restrict__ Wword, const float* __restrict__ bword,
    const float* __restrict__ w1, const float* __restrict__ b1,
    const float* __restrict__ w2, const float* __restrict__ b2,
    const float* __restrict__ w3, const float* __restrict__ b3,
    const float* __restrict__ Wfi, const float* __restrict__ bfi,
    const float* __restrict__ Wff, const float* __restrict__ bff,
    const float* __restrict__ Wfg, const float* __restrict__ bfg,
    const float* __restrict__ Wbi, const float* __restrict__ bbi,
    const float* __restrict__ Wbf, const float* __restrict__ bbf,
    const float* __restrict__ Wbg, const float* __restrict__ bbg,
    const float* __restrict__ Wout, const float* __restrict__ bout,
    float* __restrict__ ws, float* __restrict__ out)
{
  int*   flag1 = (int*)ws;
  float* XgG   = ws + 64;

  // Scan-side LDS (tiny now: only the epilogue exchange)
  __shared__ float gsum_sh[2 * NH + 4];
  // Producer-side LDS
  __shared__ int   idxs[NW];
  __shared__ float sv[5][304];          // 0: word-sum; 1..4: rows 0,1,62,63
  __shared__ float dots[5][NH];
  __shared__ float reps_s[NH];

  const int tid = threadIdx.x;
  const int b   = blockIdx.x;

  if (b < NPROD) {
    // =============================== producer ===============================
    const int s = b;
    if (tid < NW) idxs[tid] = doc[s * NW + tid];
    __syncthreads();

    // Phase B: column sums of the 64 gathered embedding rows (coalesced in e).
    for (int e = tid; e < NE; e += TPB) {
      float acc = 0.f;
#pragma unroll 16
      for (int w = 0; w < NW; ++w)
        acc += emb[(size_t)idxs[w] * NE + e];
      sv[0][e] = acc;
      sv[1][e] = emb[(size_t)idxs[0]  * NE + e];
      sv[2][e] = emb[(size_t)idxs[1]  * NE + e];
      sv[3][e] = emb[(size_t)idxs[62] * NE + e];
      sv[4][e] = emb[(size_t)idxs[63] * NE + e];
    }
    __syncthreads();

    // Phase C: 5 families x 50 outputs, 300-dots against W_word rows.
    for (int task = tid; task < 5 * NH; task += TPB) {
      const int fam = task / NH, i = task % NH;
      const float4* v4 = (const float4*)&sv[fam][0];
      const float4* w4 = (const float4*)(Wword + (size_t)i * NE);
      float a0 = 0.f, a1 = 0.f;
#pragma unroll
      for (int c = 0; c < NE / 4; ++c) {
        const float4 v = v4[c], w = w4[c];
        a0 += v.x * w.x + v.y * w.y;
        a1 += v.z * w.z + v.w * w.w;
      }
      dots[fam][i] = a0 + a1;
    }
    __syncthreads();

    // Phase D: conv means + tanh + average -> reps_s
    if (tid < NH) {
      const int o = tid;
      float m1 = 0.f, m2 = 0.f, m3 = 0.f;
      for (int i = 0; i < NH; ++i) {
        const float bw    = bword[i];
        const float total = dots[0][i] + 64.f * bw;
        const float e0  = dots[1][i] + bw;
        const float e1  = dots[2][i] + bw;
        const float e62 = dots[3][i] + bw;
        const float e63 = dots[4][i] + bw;
        m1 += w1[o * NH + i] * total;
        m2 += w2[(o * NH + i) * 2 + 0] * (total - e63)
            + w2[(o * NH + i) * 2 + 1] * (total - e0);
        m3 += w3[(o * NH + i) * 3 + 0] * (total - e62 - e63)
            + w3[(o * NH + i) * 3 + 1] * (total - e0 - e63)
            + w3[(o * NH + i) * 3 + 2] * (total - e0 - e1);
      }
      m1 = b1[o] + m1 * (1.f / 64.f);
      m2 = b2[o] + m2 * (1.f / 63.f);
      m3 = b3[o] + m3 * (1.f / 62.f);
      reps_s[o] = (fast_tanh(m1) + fast_tanh(m2) + fast_tanh(m3)) * (1.f / 3.f);
    }
    __syncthreads();

    // Phase E: x-part gate preactivations for both directions.
    for (int task = tid; task < 6 * NH; task += TPB) {
      const int dg = task / NH, j = task % NH;
      const float* Wp; const float* bp;
      switch (dg) {
        case 0: Wp = Wfi; bp = bfi; break;
        case 1: Wp = Wff; bp = bff; break;
        case 2: Wp = Wfg; bp = bfg; break;
        case 3: Wp = Wbi; bp = bbi; break;
        case 4: Wp = Wbf; bp = bbf; break;
        default: Wp = Wbg; bp = bbg; break;
      }
      float acc = bp[j];
      for (int k = 0; k < NH; ++k) acc += Wp[j * 100 + k] * reps_s[k];
      const int dir = dg / 3, gate = dg % 3;
      XgG[((dir * NS + s) * 3 + gate) * NH + j] = acc;
    }
    __syncthreads();   // all waves' Xg writes retired

    if (tid == 0) {
      __threadfence(); // write back so other XCDs see Xg
      __hip_atomic_fetch_add(flag1, 1, __ATOMIC_RELEASE, __HIP_MEMORY_SCOPE_AGENT);
    }
    return;
  }

  // ================================ scan ===================================
  // One wave per direction; wave 2 idles until the epilogue barrier.
  // All state in registers: 150 h-weights/lane, h broadcast via v_readlane.
  // ZERO LDS ops and ZERO barriers inside the 64-step loop.
  const int wid = tid >> 6, lane = tid & 63;

  if (wid < 2) {
    const int d = wid;                        // 0=fwd, 1=bwd
    const int j = (lane < NH) ? lane : 0;     // lanes 50..63 shadow lane 0

    const float* WiP = d ? Wbi : Wfi;
    const float* WfP = d ? Wbf : Wff;
    const float* WgP = d ? Wbg : Wfg;

    float wi[NH], wf[NH], wg[NH];
#pragma unroll
    for (int k = 0; k < NH; ++k) {
      wi[k] = WiP[j * 100 + 50 + k];
      wf[k] = WfP[j * 100 + 50 + k];
      wg[k] = WgP[j * 100 + 50 + k];
    }

    // Wait for all producers (whole-wave uniform spin; weights already loaded).
    while (__hip_atomic_load(flag1, __ATOMIC_ACQUIRE, __HIP_MEMORY_SCOPE_AGENT) < NPROD)
      __builtin_amdgcn_s_sleep(1);

    // Rolling 1-step-ahead global prefetch of the 3 x-preactivations.
    const float* Xd = XgG + d * NS * 3 * NH;
    const int t0 = d ? (NS - 1) : 0;
    float xi = Xd[t0 * 150 + j];
    float xf = Xd[t0 * 150 + 50 + j];
    float xg = Xd[t0 * 150 + 100 + j];

    float hj = 0.f, hs = 0.f;
#pragma unroll 1   // keep the body compact (I-cache) — do NOT unroll 64 steps
    for (int n = 0; n < NS; ++n) {
      float ai = xi, af = xf, ag = xg;
      if (n < NS - 1) {
        const int t = d ? (NS - 2 - n) : (n + 1);
        xi = Xd[t * 150 + j];
        xf = Xd[t * 150 + 50 + j];
        xg = Xd[t * 150 + 100 + j];
      }
#pragma unroll
      for (int k = 0; k < NH; ++k) {
        const float hk = lane_bcast(hj, k);   // v_readlane: no LDS, no wait
        ai = __builtin_fmaf(wi[k], hk, ai);
        af = __builtin_fmaf(wf[k], hk, af);
        ag = __builtin_fmaf(wg[k], hk, ag);
      }
      const float it = fast_sigmoid(ai);
      const float ft = fast_sigmoid(af);
      const float gt = fast_tanh(ag);
      hj = fast_tanh(it * gt + ft * hj);
      hs += hj;
    }
    if (lane < NH) gsum_sh[d * NH + lane] = hs * (1.f / 64.f);
  }
  __syncthreads();   // once, to hand gsum to wave 0

  // Epilogue (wave 0): logits + softmax
  if (wid == 0) {
    float lg = 0.f;
    if (lane < NO) {
      float acc = bout[lane];
      for (int k = 0; k < 2 * NH; ++k) acc += Wout[lane * 2 * NH + k] * gsum_sh[k];
      lg = acc;
    }
    const float l0 = __shfl(lg, 0), l1 = __shfl(lg, 1), l2 = __shfl(lg, 2),
                l3 = __shfl(lg, 3), l4 = __shfl(lg, 4);
    if (lane == 0) {
      const float m = fmaxf(fmaxf(fmaxf(l0, l1), fmaxf(l2, l3)), l4);
      const float e0 = __expf(l0 - m), e1 = __expf(l1 - m), e2 = __expf(l2 - m),
                  e3 = __expf(l3 - m), e4 = __expf(l4 - m);
      const float se = e0 + e1 + e2 + e3 + e4;
      out[0] = e0 / se; out[1] = e1 / se; out[2] = e2 / se;
      out[3] = e3 / se; out[4] = e4 / se;
    }
  }
}

extern "C" void kernel_launch(void* const* d_in, const int* in_sizes, int n_in,
                              void* d_out, int out_size, void* d_ws, size_t ws_size,
                              hipStream_t stream) {
  const int*   doc   = (const int*)  d_in[0];
  const float* emb   = (const float*)d_in[1];
  const float* Wword = (const float*)d_in[2];
  const float* bword = (const float*)d_in[3];
  const float* w1    = (const float*)d_in[4];
  const float* b1    = (const float*)d_in[5];
  const float* w2    = (const float*)d_in[6];
  const float* b2    = (const float*)d_in[7];
  const float* w3    = (const float*)d_in[8];
  const float* b3    = (const float*)d_in[9];
  const float* Wfi   = (const float*)d_in[10];
  const float* bfi   = (const float*)d_in[11];
  const float* Wff   = (const float*)d_in[12];
  const float* bff   = (const float*)d_in[13];
  const float* Wfg   = (const float*)d_in[14];
  const float* bfg   = (const float*)d_in[15];
  const float* Wbi   = (const float*)d_in[16];
  const float* bbi   = (const float*)d_in[17];
  const float* Wbf   = (const float*)d_in[18];
  const float* bbf   = (const float*)d_in[19];
  const float* Wbg   = (const float*)d_in[20];
  const float* bbg   = (const float*)d_in[21];
  const float* Wout  = (const float*)d_in[22];
  const float* bout  = (const float*)d_in[23];

  // zero the sync flag (graph-capturable async memset)
  hipMemsetAsync(d_ws, 0, 8, stream);

  k_all<<<dim3(NPROD + 1), dim3(TPB), 0, stream>>>(
      doc, emb, Wword, bword, w1, b1, w2, b2, w3, b3,
      Wfi, bfi, Wff, bff, Wfg, bfg, Wbi, bbi, Wbf, bbf, Wbg, bbg,
      Wout, bout, (float*)d_ws, (float*)d_out);
}

// Round 8
// 47.964 us; speedup vs baseline: 3.7329x; 1.6324x over previous
//
#include <hip/hip_runtime.h>
#include <math.h>

// Problem constants
#define NS 64    // sentences
#define NW 64    // words per sentence
#define NE 300   // embedding dim
#define NH 50    // hidden
#define NO 5     // output classes

// Session facts (measured):
//  - R5 k_spin: SCLK ~2.0 GHz near-idle -> clock theory dead.
//  - R1/R3/R5/R6: every scan variant spilled its weight arrays
//    (VGPR_Count 112/68/68/104 < live floats needed) -> ~1us/step scratch
//    reloads is the cross-round invariant. Fix: fit under the ~128-VGPR
//    tier via f16-packed weights (75 VGPRs) + v_dot2_f32_f16.
//  - R7: compile fail only (cvt_pkrtz returns __fp16 ext_vector, not _Float16).

typedef __fp16 half2v __attribute__((ext_vector_type(2)));

__device__ __forceinline__ float fdot2(half2v a, half2v b, float c) {
  return __builtin_amdgcn_fdot2(a, b, c, false);   // v_dot2_f32_f16
}
__device__ __forceinline__ float fast_tanh(float x) {
  x = fminf(15.f, fmaxf(-15.f, x));
  const float e = __expf(2.f * x);
  return 1.f - 2.f * __builtin_amdgcn_rcpf(e + 1.f);
}
__device__ __forceinline__ float fast_sigmoid(float x) {
  return __builtin_amdgcn_rcpf(1.f + __expf(-x));
}

// ---------------------------------------------------------------------------
// K1: per-sentence reps + x-part gate preactivations (proven in R2, absmax 0).
// ---------------------------------------------------------------------------
__global__ __launch_bounds__(512) void k_reps(
    const int* __restrict__ doc, const float* __restrict__ emb,
    const float* __restrict__ Wword, const float* __restrict__ bword,
    const float* __restrict__ w1, const float* __restrict__ b1,
    const float* __restrict__ w2, const float* __restrict__ b2,
    const float* __restrict__ w3, const float* __restrict__ b3,
    const float* __restrict__ Wfi, const float* __restrict__ bfi,
    const float* __restrict__ Wff, const float* __restrict__ bff,
    const float* __restrict__ Wfg, const float* __restrict__ bfg,
    const float* __restrict__ Wbi, const float* __restrict__ bbi,
    const float* __restrict__ Wbf, const float* __restrict__ bbf,
    const float* __restrict__ Wbg, const float* __restrict__ bbg,
    float* __restrict__ Xg)
{
  __shared__ int   idxs[NW];
  __shared__ float sv[5][304];    // 0: word-sum; 1..4: rows 0,1,62,63
  __shared__ float ph1[304];      // group-1 partial of the w-sum
  __shared__ float dots[5][NH];
  __shared__ float reps_s[NH];

  const int s = blockIdx.x, tid = threadIdx.x;
  if (tid < NW) idxs[tid] = doc[s * NW + tid];
  __syncthreads();

  // Phase B: column sums of the 64 gathered rows, 2 groups x 32-deep.
  const int p = tid >> 8, et = tid & 255;
  for (int e = et; e < NE; e += 256) {
    float acc = 0.f;
    const int w0 = p * 32;
#pragma unroll 8
    for (int w = w0; w < w0 + 32; ++w)
      acc += emb[(size_t)idxs[w] * NE + e];
    if (p == 0) sv[0][e] = acc; else ph1[e] = acc;
    if (p == 0) {
      sv[1][e] = emb[(size_t)idxs[0]  * NE + e];
      sv[2][e] = emb[(size_t)idxs[1]  * NE + e];
    } else {
      sv[3][e] = emb[(size_t)idxs[62] * NE + e];
      sv[4][e] = emb[(size_t)idxs[63] * NE + e];
    }
  }
  __syncthreads();
  if (tid < NE) sv[0][tid] += ph1[tid];
  __syncthreads();

  // Phase C: 5 families x 50 outputs, 300-dots against W_word rows.
  if (tid < 5 * NH) {
    const int fam = tid / NH, i = tid % NH;
    const float4* v4 = (const float4*)&sv[fam][0];
    const float4* w4 = (const float4*)(Wword + (size_t)i * NE);
    float a0 = 0.f, a1 = 0.f;
#pragma unroll
    for (int c = 0; c < NE / 4; ++c) {
      const float4 v = v4[c], w = w4[c];
      a0 += v.x * w.x + v.y * w.y;
      a1 += v.z * w.z + v.w * w.w;
    }
    dots[fam][i] = a0 + a1;
  }
  __syncthreads();

  // Phase D: conv means + tanh + average -> reps_s
  if (tid < NH) {
    const int o = tid;
    float m1 = 0.f, m2 = 0.f, m3 = 0.f;
    for (int i = 0; i < NH; ++i) {
      const float bw    = bword[i];
      const float total = dots[0][i] + 64.f * bw;
      const float e0  = dots[1][i] + bw;
      const float e1  = dots[2][i] + bw;
      const float e62 = dots[3][i] + bw;
      const float e63 = dots[4][i] + bw;
      m1 += w1[o * NH + i] * total;
      m2 += w2[(o * NH + i) * 2 + 0] * (total - e63)
          + w2[(o * NH + i) * 2 + 1] * (total - e0);
      m3 += w3[(o * NH + i) * 3 + 0] * (total - e62 - e63)
          + w3[(o * NH + i) * 3 + 1] * (total - e0 - e63)
          + w3[(o * NH + i) * 3 + 2] * (total - e0 - e1);
    }
    m1 = b1[o] + m1 * (1.f / 64.f);
    m2 = b2[o] + m2 * (1.f / 63.f);
    m3 = b3[o] + m3 * (1.f / 62.f);
    reps_s[o] = (fast_tanh(m1) + fast_tanh(m2) + fast_tanh(m3)) * (1.f / 3.f);
  }
  __syncthreads();

  // Phase E: x-part gate preactivations for both directions.
  if (tid < 6 * NH) {
    const int dg = tid / NH, j = tid % NH;
    const float* Wp; const float* bp;
    switch (dg) {
      case 0: Wp = Wfi; bp = bfi; break;
      case 1: Wp = Wff; bp = bff; break;
      case 2: Wp = Wfg; bp = bfg; break;
      case 3: Wp = Wbi; bp = bbi; break;
      case 4: Wp = Wbf; bp = bbf; break;
      default: Wp = Wbg; bp = bbg; break;
    }
    float acc = bp[j];
    for (int k = 0; k < NH; ++k) acc += Wp[j * 100 + k] * reps_s[k];
    const int dir = dg / 3, gate = dg % 3;
    Xg[((dir * NS + s) * 3 + gate) * NH + j] = acc;
  }
}

// ---------------------------------------------------------------------------
// K2: both scans, 1 block x 2 waves (wave = direction). Weights f16-packed:
// 3 x 25 half2 = 75 VGPRs/lane -> fits under the ~128-VGPR tier (no spill).
// h-broadcast: ds_swizzle xor-1 pairs h, cvt_pkrtz packs, 1 readlane/pair,
// v_dot2_f32_f16 accumulates in f32. Zero barriers in the 64-step loop.
// ---------------------------------------------------------------------------
__global__ __launch_bounds__(128, 1) void k_scan(
    const float* __restrict__ Xg,
    const float* __restrict__ Wfi, const float* __restrict__ Wff,
    const float* __restrict__ Wfg,
    const float* __restrict__ Wbi, const float* __restrict__ Wbf,
    const float* __restrict__ Wbg,
    const float* __restrict__ Wout, const float* __restrict__ bout,
    float* __restrict__ out)
{
  __shared__ float gsum_sh[2 * NH];

  const int tid = threadIdx.x;
  const int d   = tid >> 6;                 // wave = direction
  const int lane = tid & 63;
  const int j   = (lane < NH) ? lane : 0;   // lanes 50..63 shadow lane 0

  const float* WiP = d ? Wbi : Wfi;
  const float* WfP = d ? Wbf : Wff;
  const float* WgP = d ? Wbg : Wfg;

  // f16-packed h-weights: 25 half2 per gate (75 VGPRs total).
  half2v wi2[25], wf2[25], wg2[25];
#pragma unroll
  for (int c = 0; c < 25; ++c) {
    const int base = j * 100 + 50 + 2 * c;
    wi2[c] = __builtin_amdgcn_cvt_pkrtz(WiP[base], WiP[base + 1]);
    wf2[c] = __builtin_amdgcn_cvt_pkrtz(WfP[base], WfP[base + 1]);
    wg2[c] = __builtin_amdgcn_cvt_pkrtz(WgP[base], WgP[base + 1]);
  }

  // Rolling 1-step-ahead prefetch of the 3 x-preactivations (L2-hot).
  const float* Xd = Xg + d * NS * 3 * NH;
  const int t0 = d ? (NS - 1) : 0;
  float xi = Xd[t0 * 150 + j];
  float xf = Xd[t0 * 150 + 50 + j];
  float xg = Xd[t0 * 150 + 100 + j];

  float hj = 0.f, hs = 0.f;
#pragma unroll 1
  for (int n = 0; n < NS; ++n) {
    float ai = xi, af = xf, ag = xg;
    if (n < NS - 1) {
      const int t = d ? (NS - 2 - n) : (n + 1);
      xi = Xd[t * 150 + j];
      xf = Xd[t * 150 + 50 + j];
      xg = Xd[t * 150 + 100 + j];
    }

    // Pack (h[2c], h[2c+1]) in every even lane: partner h via swizzle xor-1.
    const float hpart = __builtin_bit_cast(float,
        __builtin_amdgcn_ds_swizzle(__builtin_bit_cast(int, hj), 0x041F));
    const half2v hpk = __builtin_amdgcn_cvt_pkrtz(hj, hpart);
    const int packed = __builtin_bit_cast(int, hpk);

#pragma unroll
    for (int c = 0; c < 25; ++c) {
      const half2v hk2 = __builtin_bit_cast(half2v,
          __builtin_amdgcn_readlane(packed, 2 * c));  // broadcast packed pair
      ai = fdot2(wi2[c], hk2, ai);
      af = fdot2(wf2[c], hk2, af);
      ag = fdot2(wg2[c], hk2, ag);
    }

    const float it = fast_sigmoid(ai);
    const float ft = fast_sigmoid(af);
    const float gt = fast_tanh(ag);
    hj = fast_tanh(it * gt + ft * hj);
    hs += hj;
  }

  if (lane < NH) gsum_sh[d * NH + lane] = hs * (1.f / 64.f);
  __syncthreads();

  // Epilogue (wave 0): logits + softmax
  if (d == 0) {
    float lg = 0.f;
    if (lane < NO) {
      float acc = bout[lane];
      for (int k = 0; k < 2 * NH; ++k) acc += Wout[lane * 2 * NH + k] * gsum_sh[k];
      lg = acc;
    }
    const float l0 = __shfl(lg, 0), l1 = __shfl(lg, 1), l2 = __shfl(lg, 2),
                l3 = __shfl(lg, 3), l4 = __shfl(lg, 4);
    if (lane == 0) {
      const float m = fmaxf(fmaxf(fmaxf(l0, l1), fmaxf(l2, l3)), l4);
      const float e0 = __expf(l0 - m), e1 = __expf(l1 - m), e2 = __expf(l2 - m),
                  e3 = __expf(l3 - m), e4 = __expf(l4 - m);
      const float se = e0 + e1 + e2 + e3 + e4;
      out[0] = e0 / se; out[1] = e1 / se; out[2] = e2 / se;
      out[3] = e3 / se; out[4] = e4 / se;
    }
  }
}

extern "C" void kernel_launch(void* const* d_in, const int* in_sizes, int n_in,
                              void* d_out, int out_size, void* d_ws, size_t ws_size,
                              hipStream_t stream) {
  const int*   doc   = (const int*)  d_in[0];
  const float* emb   = (const float*)d_in[1];
  const float* Wword = (const float*)d_in[2];
  const float* bword = (const float*)d_in[3];
  const float* w1    = (const float*)d_in[4];
  const float* b1    = (const float*)d_in[5];
  const float* w2    = (const float*)d_in[6];
  const float* b2    = (const float*)d_in[7];
  const float* w3    = (const float*)d_in[8];
  const float* b3    = (const float*)d_in[9];
  const float* Wfi   = (const float*)d_in[10];
  const float* bfi   = (const float*)d_in[11];
  const float* Wff   = (const float*)d_in[12];
  const float* bff   = (const float*)d_in[13];
  const float* Wfg   = (const float*)d_in[14];
  const float* bfg   = (const float*)d_in[15];
  const float* Wbi   = (const float*)d_in[16];
  const float* bbi   = (const float*)d_in[17];
  const float* Wbf   = (const float*)d_in[18];
  const float* bbf   = (const float*)d_in[19];
  const float* Wbg   = (const float*)d_in[20];
  const float* bbg   = (const float*)d_in[21];
  const float* Wout  = (const float*)d_in[22];
  const float* bout  = (const float*)d_in[23];

  float* Xg = (float*)d_ws + 64;   // 2*64*3*50 floats

  k_reps<<<dim3(NS), dim3(512), 0, stream>>>(
      doc, emb, Wword, bword, w1, b1, w2, b2, w3, b3,
      Wfi, bfi, Wff, bff, Wfg, bfg, Wbi, bbi, Wbf, bbf, Wbg, bbg,
      Xg);

  k_scan<<<dim3(1), dim3(128), 0, stream>>>(
      Xg, Wfi, Wff, Wfg, Wbi, Wbf, Wbg, Wout, bout, (float*)d_out);
}